// Round 9
// baseline (148.998 us; speedup 1.0000x reference)
//
#include <hip/hip_runtime.h>

typedef unsigned short u16;
typedef __bf16 bf16x8 __attribute__((ext_vector_type(8)));
typedef float  f32x16 __attribute__((ext_vector_type(16)));

__device__ __forceinline__ u16 f2bf(float f) {
    union { float f; unsigned u; } v; v.f = f;
    return (u16)((v.u + 0x7fffu + ((v.u >> 16) & 1u)) >> 16);
}

#define GLD16(gsrc, ldst) \
    __builtin_amdgcn_global_load_lds( \
        (const __attribute__((address_space(1))) void*)(gsrc), \
        (__attribute__((address_space(3))) void*)(ldst), 16, 0, 0)

// ---------------------------------------------------------------------------
// 1) s_raw[b][c] = w[b] @ mod_w[c] + mod_b[c]
// ---------------------------------------------------------------------------
__global__ __launch_bounds__(256) void lin_kernel(
    const float* __restrict__ w, const float* __restrict__ mod_w,
    const float* __restrict__ mod_b, float* __restrict__ s_raw)
{
    int gw = (blockIdx.x * 256 + threadIdx.x) >> 6;
    int lane = threadIdx.x & 63;
    int b = gw >> 9, c = gw & 511;
    const float* wr = w + b * 512;
    const float* mr = mod_w + (size_t)c * 512;
    float a = 0.f;
#pragma unroll
    for (int i = 0; i < 8; ++i)
        a = fmaf(wr[lane + i * 64], mr[lane + i * 64], a);
    for (int off = 32; off; off >>= 1) a += __shfl_down(a, off);
    if (!lane) s_raw[gw] = a + mod_b[c];
}

// ---------------------------------------------------------------------------
// 2) s_eff = LeakyReLU(LN(s_raw)) * scale
// ---------------------------------------------------------------------------
__global__ __launch_bounds__(512) void norm_kernel(
    const float* __restrict__ s_raw, const float* __restrict__ ln_g,
    const float* __restrict__ ln_b, const float* __restrict__ scale,
    float* __restrict__ s_eff)
{
    int b = blockIdx.x, c = threadIdx.x;
    __shared__ float rs[512], rq[512];
    float s = s_raw[b * 512 + c];
    rs[c] = s; rq[c] = s * s;
    __syncthreads();
    for (int off = 256; off; off >>= 1) {
        if (c < off) { rs[c] += rs[c + off]; rq[c] += rq[c + off]; }
        __syncthreads();
    }
    float mean = rs[0] * (1.f / 512.f);
    float var  = rq[0] * (1.f / 512.f) - mean * mean;
    float sn = (s - mean) * rsqrtf(var + 1e-5f) * ln_g[c] + ln_b[c];
    sn = sn >= 0.f ? sn : 0.2f * sn;
    s_eff[b * 512 + c] = sn * scale[c];
}

// ---------------------------------------------------------------------------
// 3) wsq[co][ci] = sum_p weight^2 ; wbfT[(p*64+cg)*512*8 + co*8 + cj] = bf16(w)
// ---------------------------------------------------------------------------
__global__ __launch_bounds__(256) void wsq_kernel(
    const float* __restrict__ weight, float* __restrict__ wsq, u16* __restrict__ wbfT)
{
    int idx = blockIdx.x * 256 + threadIdx.x;      // co*512+ci
    int co = idx >> 9, ci = idx & 511;
    int cg = ci >> 3, cj = ci & 7;
    const float* wp = weight + (size_t)idx * 9;
    float s = 0.f;
#pragma unroll
    for (int p = 0; p < 9; ++p) {
        float v = wp[p];
        s += v * v;
        wbfT[((size_t)(p * 64 + cg) * 512 + co) * 8 + cj] = f2bf(v);
    }
    wsq[idx] = s;
}

// ---------------------------------------------------------------------------
// 4) xs[b][h][w][c] (NHWC bf16) = bf16(x[b][c][h][w] * s_eff[b][c])
// ---------------------------------------------------------------------------
__global__ __launch_bounds__(256) void xs_kernel(
    const float* __restrict__ x, const float* __restrict__ s_eff,
    u16* __restrict__ xs)
{
    const int bh = blockIdx.x;
    const int b = bh >> 5, h = bh & 31;
    __shared__ float tile[64][33];
    for (int c0 = 0; c0 < 512; c0 += 64) {
        if (c0) __syncthreads();
        for (int idx = threadIdx.x; idx < 2048; idx += 256) {
            int c = idx >> 5, ww = idx & 31;
            tile[c][ww] = x[(((size_t)b * 512 + c0 + c) * 32 + h) * 32 + ww]
                          * s_eff[b * 512 + c0 + c];
        }
        __syncthreads();
        for (int idx = threadIdx.x; idx < 2048; idx += 256) {
            int ww = idx >> 6, c = idx & 63;
            xs[((b * 32 + h) * 32 + ww) * 512 + c0 + c] = f2bf(tile[c][ww]);
        }
    }
}

// ---------------------------------------------------------------------------
// 5) dsc[b][o] = rsqrt(sum_i s_eff[b][i]^2 * wsq[o][i] + 1e-8)
// ---------------------------------------------------------------------------
__global__ __launch_bounds__(256) void dsc_kernel(
    const float* __restrict__ s_eff, const float* __restrict__ wsq,
    float* __restrict__ dsc)
{
    int gw = (blockIdx.x * 256 + threadIdx.x) >> 6;
    int lane = threadIdx.x & 63;
    int b = gw >> 9, co = gw & 511;
    float a = 0.f;
#pragma unroll
    for (int i = 0; i < 8; ++i) {
        int cin = lane + i * 64;
        float se = s_eff[b * 512 + cin];
        a += se * se * wsq[co * 512 + cin];
    }
    for (int off = 32; off; off >>= 1) a += __shfl_down(a, off);
    if (!lane) dsc[gw] = rsqrtf(a + 1e-8f);
}

// ---------------------------------------------------------------------------
// 6) zero page for halo OOB lanes
// ---------------------------------------------------------------------------
__global__ void zfill_kernel(float* p) { p[threadIdx.x] = 0.f; }

// ---------------------------------------------------------------------------
// 7) conv, 8-phase template (T2+T3+T4+T5) on the halo structure.
//    Grid 256 = 2 mt (XCD-pinned) x 128 strips (b, 4 rows). 512 thr = 8 waves
//    (4M x 2N), wave 64co x 64px. 16 cg-rounds x 9 pos-phases.
//    A [256co][32cin] 16 KB/step, gld_lds triple-buffered (staged 2 ahead).
//    B halo [6][34][32cin] 13 KB/cg, double-buffered (staged at phase 4).
//    Phase: reads | issues | barrier | lgkm0 | setprio MFMA | vmcnt(N) barrier.
// ---------------------------------------------------------------------------
__global__ __launch_bounds__(512) void conv_kernel(
    const u16* __restrict__ wbfT,  // [576 kflat8][512 co][8]
    const u16* __restrict__ xs,    // [16][32][32][512]
    const float* __restrict__ dsc, // [16][512]
    const u16* __restrict__ zp,    // >=16B zeros
    float* __restrict__ out)       // [16][512][32][32]
{
    __shared__ __align__(16) u16 ldsA[3 * 8192];   // 3 x 16 KB
    __shared__ __align__(16) u16 ldsB[2 * 8192];   // 2 x (13056 used + pad)

    const int tid  = threadIdx.x;
    const int lane = tid & 63;
    const int wv   = tid >> 6;       // 0..7
    const int wm   = wv >> 1;        // 0..3 M-wave
    const int wn   = wv & 1;         // 0..1 N-wave
    const int l31  = lane & 31;
    const int kc8  = lane >> 5;

    const int bx = blockIdx.x;       // 256 blocks
    const int mt = bx & 1;           // XCD-pinned cout half
    const int nt = bx >> 1;          // 0..127
    const int b  = nt >> 3;
    const int h0 = (nt & 7) << 2;    // 4 output rows

    const u16* xsb = xs + (size_t)b * (32 * 32 * 512);
    char* ldsAc = (char*)ldsA;
    char* ldsBc = (char*)ldsB;

    // ---- A staging: 1024 chunks; thread -> ch = tid, tid+512 ----
    // chunk ch: co=ch>>2, phys slot=ch&3 holds kc = slot^((co>>1)&3)
    const u16* asrc0; const u16* asrc1;
    {
        int co0 = tid >> 2,        kc0 = (tid & 3) ^ ((co0 >> 1) & 3);
        int co1 = (tid + 512) >> 2, kc1 = ((tid + 512) & 3) ^ ((co1 >> 1) & 3);
        asrc0 = wbfT + ((size_t)kc0 * 512 + mt * 256 + co0) * 8;
        asrc1 = wbfT + ((size_t)kc1 * 512 + mt * 256 + co1) * 8;
    }
    auto issueA = [&](int pos_st, int cg_st, int buf) {
        size_t off = (size_t)(pos_st * 64 + cg_st * 4) * 4096;
        char* d = ldsAc + buf * 16384 + wv * 1024;
        GLD16(asrc0 + off, d);
        GLD16(asrc1 + off, d + 8192);
    };

    // ---- B staging: 816 chunks (+pad); ch = tid, tid+512 (uniform issue) ----
    const u16* bsrc[2]; bool binb[2];
#pragma unroll
    for (int k = 0; k < 2; ++k) {
        int ch = tid + k * 512;
        int p = ch >> 2, slot = ch & 3;
        int kc = slot ^ ((p >> 1) & 3);
        int rr = p / 34, cc = p % 34;
        int hh = h0 - 1 + rr, ww = cc - 1;
        binb[k] = (ch < 816) && ((unsigned)hh < 32u) && ((unsigned)ww < 32u);
        bsrc[k] = xsb + (hh * 32 + ww) * 512 + kc * 8;
    }
    auto issueB = [&](int buf, int c0) {
        char* d = ldsBc + buf * 16384 + wv * 1024;
        GLD16(binb[0] ? bsrc[0] + c0 : zp, d);           // uniform: 2 instr/wave
        GLD16(binb[1] ? bsrc[1] + c0 : zp, d + 8192);    // pad region if ch>=816
    };

    // ---- frag read constants ----
    const int aswz = (l31 >> 1) & 3;     // A phys = kc ^ aswz
    f32x16 acc[2][2] = {};

    // ---- prologue: A(0,0)->buf0, B(cg0)->buf0, A(1,0)->buf1 ----
    issueA(0, 0, 0);
    issueB(0, 0);
    issueA(1, 0, 1);
    asm volatile("s_waitcnt vmcnt(2)" ::: "memory");   // A(1) may fly
    __builtin_amdgcn_s_barrier();

    for (int r = 0; r < 16; ++r) {
        const char* bb = ldsBc + (r & 1) * 16384;
        const bool last = (r == 15);

#pragma unroll
        for (int s = 0; s < 9; ++s) {
            const int kh = s / 3, kw = s % 3;
            const char* ab = ldsAc + (s % 3) * 16384;

            // ---- ds_read frags for pos s ----
            bf16x8 af[2][2], bfv[2][2];
#pragma unroll
            for (int mf = 0; mf < 2; ++mf)
#pragma unroll
                for (int kk = 0; kk < 2; ++kk) {
                    int co = wm * 64 + mf * 32 + l31;
                    int ph = (kk * 2 + kc8) ^ aswz;
                    af[mf][kk] = *reinterpret_cast<const bf16x8*>(
                        ab + co * 64 + ph * 16);
                }
#pragma unroll
            for (int kk = 0; kk < 2; ++kk)
#pragma unroll
                for (int nf = 0; nf < 2; ++nf) {
                    int p = (wn * 2 + nf + kh) * 34 + l31 + kw;
                    int ph = (kk * 2 + kc8) ^ ((p >> 1) & 3);
                    bfv[kk][nf] = *reinterpret_cast<const bf16x8*>(
                        bb + p * 64 + ph * 16);
                }

            // ---- stage issues (2 steps ahead; B for cg+1 at s==4) ----
            if (s <= 6)      issueA(s + 2, r, (s + 2) % 3);
            else if (!last)  issueA(s - 7, r + 1, (s + 2) % 3);
            if (s == 4 && !last) issueB((r + 1) & 1, (r + 1) * 32);

            __builtin_amdgcn_s_barrier();
            asm volatile("s_waitcnt lgkmcnt(0)" ::: "memory");
            __builtin_amdgcn_sched_barrier(0);

            __builtin_amdgcn_s_setprio(1);
#pragma unroll
            for (int kk = 0; kk < 2; ++kk) {
                acc[0][0] = __builtin_amdgcn_mfma_f32_32x32x16_bf16(af[0][kk], bfv[kk][0], acc[0][0], 0, 0, 0);
                acc[0][1] = __builtin_amdgcn_mfma_f32_32x32x16_bf16(af[0][kk], bfv[kk][1], acc[0][1], 0, 0, 0);
                acc[1][0] = __builtin_amdgcn_mfma_f32_32x32x16_bf16(af[1][kk], bfv[kk][0], acc[1][0], 0, 0, 0);
                acc[1][1] = __builtin_amdgcn_mfma_f32_32x32x16_bf16(af[1][kk], bfv[kk][1], acc[1][1], 0, 0, 0);
            }
            __builtin_amdgcn_s_setprio(0);
            __builtin_amdgcn_sched_barrier(0);

            // ---- counted vmcnt + barrier (ledger: A=2/phase, B=2 at s4) ----
            if (!last) {
                if (s == 4 || s == 5) asm volatile("s_waitcnt vmcnt(4)" ::: "memory");
                else                  asm volatile("s_waitcnt vmcnt(2)" ::: "memory");
                __builtin_amdgcn_s_barrier();
            } else {
                if (s <= 6) {
                    asm volatile("s_waitcnt vmcnt(2)" ::: "memory");
                    __builtin_amdgcn_s_barrier();
                } else if (s == 7) {
                    asm volatile("s_waitcnt vmcnt(0)" ::: "memory");
                    __builtin_amdgcn_s_barrier();
                }   // s==8 of last round: fall through to epilogue
            }
        }
    }

    // ---- epilogue: C/D col=lane&31, row=(q&3)+8*(q>>2)+4*(lane>>5) ----
    const float* db = dsc + b * 512;
#pragma unroll
    for (int mf = 0; mf < 2; ++mf) {
#pragma unroll
        for (int nf = 0; nf < 2; ++nf) {
            const int px = wn * 64 + nf * 32 + l31;
            const int h = h0 + (px >> 5), w = px & 31;
#pragma unroll
            for (int q = 0; q < 16; ++q) {
                int row = (q & 3) + 8 * (q >> 2) + 4 * kc8;
                int co  = mt * 256 + wm * 64 + mf * 32 + row;
                out[(((size_t)b * 512 + co) * 32 + h) * 32 + w]
                    = acc[mf][nf][q] * db[co];
            }
        }
    }
}

// ---------------------------------------------------------------------------
extern "C" void kernel_launch(void* const* d_in, const int* in_sizes, int n_in,
                              void* d_out, int out_size, void* d_ws, size_t ws_size,
                              hipStream_t stream) {
    const float* x      = (const float*)d_in[0];
    const float* w      = (const float*)d_in[1];
    const float* mod_w  = (const float*)d_in[2];
    const float* mod_b  = (const float*)d_in[3];
    const float* ln_g   = (const float*)d_in[4];
    const float* ln_b   = (const float*)d_in[5];
    const float* weight = (const float*)d_in[6];
    const float* scale  = (const float*)d_in[7];
    float* out = (float*)d_out;

    char* ws = (char*)d_ws;
    float* s_raw = (float*)(ws);                     // 32 KB, reused as dsc
    float* dsc   = (float*)(ws);
    float* s_eff = (float*)(ws + 32768);             // 32 KB; head reused as zeros page
    float* wsq   = (float*)(ws + 65536);             // 1 MB
    u16*   wbfT  = (u16*)(ws + 65536 + 1048576);     // 4.5 MB
    u16*   xs    = (u16*)(ws + 65536 + 1048576 + 4718592);  // 16.78 MB
    if (ws_size < 22609920u) return;

    lin_kernel <<<2048, 256, 0, stream>>>(w, mod_w, mod_b, s_raw);
    wsq_kernel <<<1024, 256, 0, stream>>>(weight, wsq, wbfT);
    norm_kernel<<<16, 512, 0, stream>>>(s_raw, ln_g, ln_b, scale, s_eff);
    xs_kernel  <<<512, 256, 0, stream>>>(x, s_eff, xs);
    dsc_kernel <<<2048, 256, 0, stream>>>(s_eff, wsq, dsc);
    zfill_kernel<<<1, 1024, 0, stream>>>(s_eff);     // zeros page (s_eff dead now)
    conv_kernel<<<256, 512, 0, stream>>>(wbfT, xs, dsc, (const u16*)s_eff, out);
}

// Round 10
// 144.682 us; speedup vs baseline: 1.0298x; 1.0298x over previous
//
#include <hip/hip_runtime.h>

typedef unsigned short u16;
typedef __bf16 bf16x8 __attribute__((ext_vector_type(8)));
typedef float  f32x16 __attribute__((ext_vector_type(16)));

__device__ __forceinline__ u16 f2bf(float f) {
    union { float f; unsigned u; } v; v.f = f;
    return (u16)((v.u + 0x7fffu + ((v.u >> 16) & 1u)) >> 16);
}

#define GLD16(gsrc, ldst) \
    __builtin_amdgcn_global_load_lds( \
        (const __attribute__((address_space(1))) void*)(gsrc), \
        (__attribute__((address_space(3))) void*)(ldst), 16, 0, 0)

// ---------------------------------------------------------------------------
// 1) s_raw[b][c] = w[b] @ mod_w[c] + mod_b[c]
// ---------------------------------------------------------------------------
__global__ __launch_bounds__(256) void lin_kernel(
    const float* __restrict__ w, const float* __restrict__ mod_w,
    const float* __restrict__ mod_b, float* __restrict__ s_raw)
{
    int gw = (blockIdx.x * 256 + threadIdx.x) >> 6;
    int lane = threadIdx.x & 63;
    int b = gw >> 9, c = gw & 511;
    const float* wr = w + b * 512;
    const float* mr = mod_w + (size_t)c * 512;
    float a = 0.f;
#pragma unroll
    for (int i = 0; i < 8; ++i)
        a = fmaf(wr[lane + i * 64], mr[lane + i * 64], a);
    for (int off = 32; off; off >>= 1) a += __shfl_down(a, off);
    if (!lane) s_raw[gw] = a + mod_b[c];
}

// ---------------------------------------------------------------------------
// 2) s_eff = LeakyReLU(LN(s_raw)) * scale
// ---------------------------------------------------------------------------
__global__ __launch_bounds__(512) void norm_kernel(
    const float* __restrict__ s_raw, const float* __restrict__ ln_g,
    const float* __restrict__ ln_b, const float* __restrict__ scale,
    float* __restrict__ s_eff)
{
    int b = blockIdx.x, c = threadIdx.x;
    __shared__ float rs[512], rq[512];
    float s = s_raw[b * 512 + c];
    rs[c] = s; rq[c] = s * s;
    __syncthreads();
    for (int off = 256; off; off >>= 1) {
        if (c < off) { rs[c] += rs[c + off]; rq[c] += rq[c + off]; }
        __syncthreads();
    }
    float mean = rs[0] * (1.f / 512.f);
    float var  = rq[0] * (1.f / 512.f) - mean * mean;
    float sn = (s - mean) * rsqrtf(var + 1e-5f) * ln_g[c] + ln_b[c];
    sn = sn >= 0.f ? sn : 0.2f * sn;
    s_eff[b * 512 + c] = sn * scale[c];
}

// ---------------------------------------------------------------------------
// 3) wsq[co][ci] = sum_p weight^2 ; wbfT[(p*64+cg)*512*8 + co*8 + cj] = bf16(w)
// ---------------------------------------------------------------------------
__global__ __launch_bounds__(256) void wsq_kernel(
    const float* __restrict__ weight, float* __restrict__ wsq, u16* __restrict__ wbfT)
{
    int idx = blockIdx.x * 256 + threadIdx.x;      // co*512+ci
    int co = idx >> 9, ci = idx & 511;
    int cg = ci >> 3, cj = ci & 7;
    const float* wp = weight + (size_t)idx * 9;
    float s = 0.f;
#pragma unroll
    for (int p = 0; p < 9; ++p) {
        float v = wp[p];
        s += v * v;
        wbfT[((size_t)(p * 64 + cg) * 512 + co) * 8 + cj] = f2bf(v);
    }
    wsq[idx] = s;
}

// ---------------------------------------------------------------------------
// 4) xs[b][h][w][c] (NHWC bf16) = bf16(x[b][c][h][w] * s_eff[b][c])
// ---------------------------------------------------------------------------
__global__ __launch_bounds__(256) void xs_kernel(
    const float* __restrict__ x, const float* __restrict__ s_eff,
    u16* __restrict__ xs)
{
    const int bh = blockIdx.x;
    const int b = bh >> 5, h = bh & 31;
    __shared__ float tile[64][33];
    for (int c0 = 0; c0 < 512; c0 += 64) {
        if (c0) __syncthreads();
        for (int idx = threadIdx.x; idx < 2048; idx += 256) {
            int c = idx >> 5, ww = idx & 31;
            tile[c][ww] = x[(((size_t)b * 512 + c0 + c) * 32 + h) * 32 + ww]
                          * s_eff[b * 512 + c0 + c];
        }
        __syncthreads();
        for (int idx = threadIdx.x; idx < 2048; idx += 256) {
            int ww = idx >> 6, c = idx & 63;
            xs[((b * 32 + h) * 32 + ww) * 512 + c0 + c] = f2bf(tile[c][ww]);
        }
    }
}

// ---------------------------------------------------------------------------
// 5) dsc[b][o] = rsqrt(sum_i s_eff[b][i]^2 * wsq[o][i] + 1e-8)
// ---------------------------------------------------------------------------
__global__ __launch_bounds__(256) void dsc_kernel(
    const float* __restrict__ s_eff, const float* __restrict__ wsq,
    float* __restrict__ dsc)
{
    int gw = (blockIdx.x * 256 + threadIdx.x) >> 6;
    int lane = threadIdx.x & 63;
    int b = gw >> 9, co = gw & 511;
    float a = 0.f;
#pragma unroll
    for (int i = 0; i < 8; ++i) {
        int cin = lane + i * 64;
        float se = s_eff[b * 512 + cin];
        a += se * se * wsq[co * 512 + cin];
    }
    for (int off = 32; off; off >>= 1) a += __shfl_down(a, off);
    if (!lane) dsc[gw] = rsqrtf(a + 1e-8f);
}

// ---------------------------------------------------------------------------
// 6) zero page for halo OOB lanes
// ---------------------------------------------------------------------------
__global__ void zfill_kernel(float* p) { p[threadIdx.x] = 0.f; }

// ---------------------------------------------------------------------------
// 7) conv, halo-restage, 4 blocks/CU at UNCHANGED per-CU traffic (clean TLP
//    test vs R6: same halo 2x re-read, same A stream, same LDS read count).
//    Grid 1024 = 4 mt (bx&3, fixed per XCD -> 1.18 MB A-slice L2-resident)
//    x 256 two-row strips. Block 256 thr = 4 waves (2M x 2N),
//    wave 64co x 32px, BM=128, BN=64.
//    Per 32-cin round: stage halo [4][34][32] once (8704 B, dbuf), 9 taps.
//    A (global, L1-shared across 4 co-resident blocks) + B (LDS) both
//    prefetched one pos ahead into ping-pong regs. Counted-vmcnt barrier,
//    setprio around MFMA.
// ---------------------------------------------------------------------------
__global__ __launch_bounds__(256, 4) void conv_kernel(
    const u16* __restrict__ wbfT,  // [576 kflat8][512 co][8]
    const u16* __restrict__ xs,    // [16][32][32][512]
    const float* __restrict__ dsc, // [16][512]
    const u16* __restrict__ zp,    // >=16B zeros
    float* __restrict__ out)       // [16][512][32][32]
{
    __shared__ __align__(16) u16 lds[2 * 544 * 8];   // 2 x 8704 B

    const int tid  = threadIdx.x;
    const int lane = tid & 63;
    const int wv   = tid >> 6;       // 0..3
    const int wm   = wv >> 1;        // 0..1  M-wave (64 co)
    const int wn   = wv & 1;         // 0..1  N-wave (row select)
    const int l31  = lane & 31;
    const int kc8  = lane >> 5;

    const int bx = blockIdx.x;       // 1024 blocks
    const int mt = bx & 3;           // cout quarter, fixed per XCD
    const int nt = bx >> 2;          // 0..255
    const int b  = nt >> 4;
    const int h0 = (nt & 15) << 1;   // output rows h0, h0+1

    const u16* xsb = xs + (size_t)b * (32 * 32 * 512);

    // ---- halo staging descriptors: 544 chunks = 136 p x 4 slots x 16B ----
    const u16* sb[3]; bool sval[3], inb[3];
#pragma unroll
    for (int k = 0; k < 3; ++k) {
        int ch = tid + k * 256;
        sval[k] = ch < 544;
        int p = ch >> 2, slot = ch & 3;
        int kc = slot ^ ((p >> 1) & 3);
        int rr = p / 34, cc = p % 34;
        int hh = h0 - 1 + rr, ww = cc - 1;
        inb[k] = sval[k] && ((unsigned)hh < 32u) && ((unsigned)ww < 32u);
        sb[k] = xsb + (hh * 32 + ww) * 512 + kc * 8;
    }
    char* ldsb = (char*)lds;
    char* wdst = ldsb + wv * 1024;   // wave-uniform; HW adds lane*16

    auto stage = [&](int buf, int c0) {
        char* d = wdst + buf * 8704;
        GLD16(inb[0] ? sb[0] + c0 : zp, d);
        GLD16(inb[1] ? sb[1] + c0 : zp, d + 4096);
        if (sval[2]) GLD16(inb[2] ? sb[2] + c0 : zp, d + 8192);
    };

    // ---- A pointers: co = mt*128 + wm*64 + mf*32 + l31, kc-grp kk*2+kc8 ----
    const u16* apb[2];
#pragma unroll
    for (int mf = 0; mf < 2; ++mf)
        apb[mf] = wbfT + ((size_t)kc8 * 512 + mt * 128 + wm * 64 + mf * 32 + l31) * 8;

    uint4 aA[2][2], aB[2][2];        // ping/pong [mf][kk]
    auto loadA = [&](uint4 (&dst)[2][2], int pos, int c0g) {
#pragma unroll
        for (int mf = 0; mf < 2; ++mf)
#pragma unroll
            for (int kk = 0; kk < 2; ++kk)
                dst[mf][kk] = *reinterpret_cast<const uint4*>(
                    apb[mf] + ((size_t)(pos * 64 + c0g) + kk * 2) * 4096);
    };

    // ---- B register ping-pong: [kk], row picked by wn ----
    bf16x8 bvA[2], bvB[2];
    auto loadB = [&](bf16x8 (&dst)[2], const char* base, int pos) {
        const int kh = pos / 3, kw = pos % 3;
        const int p = (wn + kh) * 34 + l31 + kw;
#pragma unroll
        for (int kk = 0; kk < 2; ++kk) {
            const int sk = kk * 2 + kc8;
            dst[kk] = *reinterpret_cast<const bf16x8*>(
                base + p * 64 + ((sk ^ ((p >> 1) & 3)) << 4));
        }
    };

    f32x16 acc[2] = {};
    auto domfma = [&](uint4 (&af)[2][2], bf16x8 (&bf)[2]) {
        __builtin_amdgcn_s_setprio(1);
#pragma unroll
        for (int kk = 0; kk < 2; ++kk)
#pragma unroll
            for (int mf = 0; mf < 2; ++mf) {
                bf16x8 av = *reinterpret_cast<const bf16x8*>(&af[mf][kk]);
                acc[mf] = __builtin_amdgcn_mfma_f32_32x32x16_bf16(
                    av, bf[kk], acc[mf], 0, 0, 0);
            }
        __builtin_amdgcn_s_setprio(0);
    };

    stage(0, 0);
    loadA(aA, 0, 0);
    __syncthreads();                 // one-time full drain: buf0 resident

    for (int r = 0; r < 16; ++r) {
        const int c0g = r * 4;
        const char* base = ldsb + (r & 1) * 8704;
        if (r < 15) stage((r + 1) & 1, (r + 1) * 32);   // flies over 9-tap phase
        loadB(bvA, base, 0);

#pragma unroll
        for (int pos = 0; pos < 9; ++pos) {
            if (pos < 8) {
                if ((pos & 1) == 0) { loadA(aB, pos + 1, c0g); loadB(bvB, base, pos + 1); }
                else                { loadA(aA, pos + 1, c0g); loadB(bvA, base, pos + 1); }
            } else if (r < 15) {
                loadA(aB, 0, c0g + 4);       // next round pos0 A
            }
            if ((pos & 1) == 0) domfma(aA, bvA);
            else                domfma(aB, bvB);
        }
        if (r < 15) {
#pragma unroll
            for (int mf = 0; mf < 2; ++mf)
#pragma unroll
                for (int kk = 0; kk < 2; ++kk) aA[mf][kk] = aB[mf][kk];
            // per-wave ledger: stages (oldest) must drain; 4 newest A-loads fly
            asm volatile("s_waitcnt vmcnt(4)" ::: "memory");
            __builtin_amdgcn_s_barrier();
            asm volatile("" ::: "memory");
        }
    }

    // ---- epilogue: C/D col=lane&31, row=(q&3)+8*(q>>2)+4*(lane>>5) ----
    const float* db = dsc + b * 512;
    const int h = h0 + wn, w = l31;
#pragma unroll
    for (int mf = 0; mf < 2; ++mf) {
#pragma unroll
        for (int q = 0; q < 16; ++q) {
            int row = (q & 3) + 8 * (q >> 2) + 4 * kc8;
            int co  = mt * 128 + wm * 64 + mf * 32 + row;
            out[(((size_t)b * 512 + co) * 32 + h) * 32 + w]
                = acc[mf][q] * db[co];
        }
    }
}

// ---------------------------------------------------------------------------
extern "C" void kernel_launch(void* const* d_in, const int* in_sizes, int n_in,
                              void* d_out, int out_size, void* d_ws, size_t ws_size,
                              hipStream_t stream) {
    const float* x      = (const float*)d_in[0];
    const float* w      = (const float*)d_in[1];
    const float* mod_w  = (const float*)d_in[2];
    const float* mod_b  = (const float*)d_in[3];
    const float* ln_g   = (const float*)d_in[4];
    const float* ln_b   = (const float*)d_in[5];
    const float* weight = (const float*)d_in[6];
    const float* scale  = (const float*)d_in[7];
    float* out = (float*)d_out;

    char* ws = (char*)d_ws;
    float* s_raw = (float*)(ws);                     // 32 KB, reused as dsc
    float* dsc   = (float*)(ws);
    float* s_eff = (float*)(ws + 32768);             // 32 KB; head reused as zeros page
    float* wsq   = (float*)(ws + 65536);             // 1 MB
    u16*   wbfT  = (u16*)(ws + 65536 + 1048576);     // 4.5 MB
    u16*   xs    = (u16*)(ws + 65536 + 1048576 + 4718592);  // 16.78 MB
    if (ws_size < 22609920u) return;

    lin_kernel <<<2048, 256, 0, stream>>>(w, mod_w, mod_b, s_raw);
    wsq_kernel <<<1024, 256, 0, stream>>>(weight, wsq, wbfT);
    norm_kernel<<<16, 512, 0, stream>>>(s_raw, ln_g, ln_b, scale, s_eff);
    xs_kernel  <<<512, 256, 0, stream>>>(x, s_eff, xs);
    dsc_kernel <<<2048, 256, 0, stream>>>(s_eff, wsq, dsc);
    zfill_kernel<<<1, 1024, 0, stream>>>(s_eff);     // zeros page (s_eff dead now)
    conv_kernel<<<1024, 256, 0, stream>>>(wbfT, xs, dsc, (const u16*)s_eff, out);
}

// Round 11
// 113.865 us; speedup vs baseline: 1.3086x; 1.2707x over previous
//
#include <hip/hip_runtime.h>

typedef unsigned short u16;
typedef __bf16 bf16x8 __attribute__((ext_vector_type(8)));
typedef float  f32x16 __attribute__((ext_vector_type(16)));

__device__ __forceinline__ u16 f2bf(float f) {
    union { float f; unsigned u; } v; v.f = f;
    return (u16)((v.u + 0x7fffu + ((v.u >> 16) & 1u)) >> 16);
}

#define GLD16(gsrc, ldst) \
    __builtin_amdgcn_global_load_lds( \
        (const __attribute__((address_space(1))) void*)(gsrc), \
        (__attribute__((address_space(3))) void*)(ldst), 16, 0, 0)

// ---------------------------------------------------------------------------
// 1) s_raw[b][c] = w[b] @ mod_w[c] + mod_b[c]
// ---------------------------------------------------------------------------
__global__ __launch_bounds__(256) void lin_kernel(
    const float* __restrict__ w, const float* __restrict__ mod_w,
    const float* __restrict__ mod_b, float* __restrict__ s_raw)
{
    int gw = (blockIdx.x * 256 + threadIdx.x) >> 6;
    int lane = threadIdx.x & 63;
    int b = gw >> 9, c = gw & 511;
    const float* wr = w + b * 512;
    const float* mr = mod_w + (size_t)c * 512;
    float a = 0.f;
#pragma unroll
    for (int i = 0; i < 8; ++i)
        a = fmaf(wr[lane + i * 64], mr[lane + i * 64], a);
    for (int off = 32; off; off >>= 1) a += __shfl_down(a, off);
    if (!lane) s_raw[gw] = a + mod_b[c];
}

// ---------------------------------------------------------------------------
// 2) s_eff = LeakyReLU(LN(s_raw)) * scale
// ---------------------------------------------------------------------------
__global__ __launch_bounds__(512) void norm_kernel(
    const float* __restrict__ s_raw, const float* __restrict__ ln_g,
    const float* __restrict__ ln_b, const float* __restrict__ scale,
    float* __restrict__ s_eff)
{
    int b = blockIdx.x, c = threadIdx.x;
    __shared__ float rs[512], rq[512];
    float s = s_raw[b * 512 + c];
    rs[c] = s; rq[c] = s * s;
    __syncthreads();
    for (int off = 256; off; off >>= 1) {
        if (c < off) { rs[c] += rs[c + off]; rq[c] += rq[c + off]; }
        __syncthreads();
    }
    float mean = rs[0] * (1.f / 512.f);
    float var  = rq[0] * (1.f / 512.f) - mean * mean;
    float sn = (s - mean) * rsqrtf(var + 1e-5f) * ln_g[c] + ln_b[c];
    sn = sn >= 0.f ? sn : 0.2f * sn;
    s_eff[b * 512 + c] = sn * scale[c];
}

// ---------------------------------------------------------------------------
// 3) wsq[co][ci] = sum_p weight^2 ; wbfT[(p*64+cg)*512*8 + co*8 + cj] = bf16(w)
// ---------------------------------------------------------------------------
__global__ __launch_bounds__(256) void wsq_kernel(
    const float* __restrict__ weight, float* __restrict__ wsq, u16* __restrict__ wbfT)
{
    int idx = blockIdx.x * 256 + threadIdx.x;      // co*512+ci
    int co = idx >> 9, ci = idx & 511;
    int cg = ci >> 3, cj = ci & 7;
    const float* wp = weight + (size_t)idx * 9;
    float s = 0.f;
#pragma unroll
    for (int p = 0; p < 9; ++p) {
        float v = wp[p];
        s += v * v;
        wbfT[((size_t)(p * 64 + cg) * 512 + co) * 8 + cj] = f2bf(v);
    }
    wsq[idx] = s;
}

// ---------------------------------------------------------------------------
// 4) xs[b][h][w][c] (NHWC bf16) = bf16(x[b][c][h][w] * s_eff[b][c])
// ---------------------------------------------------------------------------
__global__ __launch_bounds__(256) void xs_kernel(
    const float* __restrict__ x, const float* __restrict__ s_eff,
    u16* __restrict__ xs)
{
    const int bh = blockIdx.x;
    const int b = bh >> 5, h = bh & 31;
    __shared__ float tile[64][33];
    for (int c0 = 0; c0 < 512; c0 += 64) {
        if (c0) __syncthreads();
        for (int idx = threadIdx.x; idx < 2048; idx += 256) {
            int c = idx >> 5, ww = idx & 31;
            tile[c][ww] = x[(((size_t)b * 512 + c0 + c) * 32 + h) * 32 + ww]
                          * s_eff[b * 512 + c0 + c];
        }
        __syncthreads();
        for (int idx = threadIdx.x; idx < 2048; idx += 256) {
            int ww = idx >> 6, c = idx & 63;
            xs[((b * 32 + h) * 32 + ww) * 512 + c0 + c] = f2bf(tile[c][ww]);
        }
    }
}

// ---------------------------------------------------------------------------
// 5) dsc[b][o] = rsqrt(sum_i s_eff[b][i]^2 * wsq[o][i] + 1e-8)
// ---------------------------------------------------------------------------
__global__ __launch_bounds__(256) void dsc_kernel(
    const float* __restrict__ s_eff, const float* __restrict__ wsq,
    float* __restrict__ dsc)
{
    int gw = (blockIdx.x * 256 + threadIdx.x) >> 6;
    int lane = threadIdx.x & 63;
    int b = gw >> 9, co = gw & 511;
    float a = 0.f;
#pragma unroll
    for (int i = 0; i < 8; ++i) {
        int cin = lane + i * 64;
        float se = s_eff[b * 512 + cin];
        a += se * se * wsq[co * 512 + cin];
    }
    for (int off = 32; off; off >>= 1) a += __shfl_down(a, off);
    if (!lane) dsc[gw] = rsqrtf(a + 1e-8f);
}

// ---------------------------------------------------------------------------
// 6) zero page for halo OOB lanes
// ---------------------------------------------------------------------------
__global__ void zfill_kernel(float* p) { p[threadIdx.x] = 0.f; }

// ---------------------------------------------------------------------------
// 7) conv, m201-style phase machine. Grid 256 = 2 mt (XCD-parity) x 128
//    4-row strips. 512 thr = 8 waves (4M x 2N), wave 64co x 64px.
//    BM=256, BN=128. Round = 32-cin group; 3 phases/round (phase = kernel
//    row kh=phi, taps kw=pp 0..2).
//    A: LDS [2 buf][3 pp][4 kc][256 co][8cin] 48KB/buf, gld_lds-staged one
//       phase ahead.  B: LDS [2 buf][4 kc][204 p][8cin] 16KB/buf (padded),
//       staged one round ahead at phi=1.  kc-major => frag reads are
//       consecutive-16B per lane = conflict-free (2-way).
//    Phase: {24 ds_read | stage issues | barrier | lgkm0 | 24 MFMA (setprio) |
//            vmcnt(0) | barrier}.  Only staging uses vmcnt (no FIFO poison).
// ---------------------------------------------------------------------------
__global__ __launch_bounds__(512, 2) void conv_kernel(
    const u16* __restrict__ wbfT,  // [576 kflat8][512 co][8]
    const u16* __restrict__ xs,    // [16][32][32][512]
    const float* __restrict__ dsc, // [16][512]
    const u16* __restrict__ zp,    // >=16B zeros
    float* __restrict__ out)       // [16][512][32][32]
{
    __shared__ __align__(16) u16 ldsA[2][24576];   // 2 x 48 KB
    __shared__ __align__(16) u16 ldsB[2][8192];    // 2 x 16 KB (13056 + pad)

    const int tid  = threadIdx.x;
    const int lane = tid & 63;
    const int wv   = tid >> 6;       // 0..7
    const int wm   = wv >> 1;        // 0..3  M-wave (64 co each)
    const int wn   = wv & 1;         // 0..1  N-wave (64 px each)
    const int l31  = lane & 31;
    const int kc8  = lane >> 5;

    const int bx = blockIdx.x;       // 256 blocks
    const int mt = bx & 1;           // XCD-parity-pinned cout half
    const int nt = bx >> 1;          // 0..127
    const int b  = nt >> 3;
    const int h0 = (nt & 7) << 2;    // 4 output rows

    const u16* xsb = xs + (size_t)b * (32 * 32 * 512);

    // ---- A staging: 3072 chunks; ch = tid + k*512, k<6 ----
    // ch = pp*1024 + kc*256 + co ; LDS dest = ch*16 (linear)
    const u16* asrc[6];
#pragma unroll
    for (int k = 0; k < 6; ++k) {
        int ch = tid + k * 512;
        int pp = ch >> 10, kc = (ch >> 8) & 3, co = ch & 255;
        // initial staged target: (r=0, phi=0) -> pos = pp, kflat8 = pp*64+kc
        asrc[k] = wbfT + ((size_t)(pp * 64 + kc) * 512 + mt * 256 + co) * 8;
    }
    auto stageA = [&](int buf) {
        char* d = (char*)ldsA[buf] + wv * 1024;
#pragma unroll
        for (int k = 0; k < 6; ++k) GLD16(asrc[k], d + k * 8192);
    };
    auto advA = [&](long dkf) {      // dkf in kflat8 units (x4096 u16)
#pragma unroll
        for (int k = 0; k < 6; ++k) asrc[k] += dkf * 4096;
    };

    // ---- B staging: 816 chunks (+pad to 1024); ch = tid + k*512, k<2 ----
    // ch = kc*204 + p (ch<816); LDS dest = ch*16 (linear)
    const u16* bsrc[2]; bool binb[2];
#pragma unroll
    for (int k = 0; k < 2; ++k) {
        int ch = tid + k * 512;
        int kc = ch / 204, p = ch % 204;
        int rr = p / 34, cc = p % 34;
        int hh = h0 - 1 + rr, ww = cc - 1;
        binb[k] = (ch < 816) && ((unsigned)hh < 32u) && ((unsigned)ww < 32u);
        bsrc[k] = xsb + (hh * 32 + ww) * 512 + kc * 8;
    }
    auto stageB = [&](int buf) {
        char* d = (char*)ldsB[buf] + wv * 1024;
        GLD16(binb[0] ? bsrc[0] : zp, d);
        GLD16(binb[1] ? bsrc[1] : zp, d + 8192);
    };

    f32x16 acc[2][2] = {};

    // ---- prologue: A(r0,phi0)->buf0, B(r0)->buf0 ----
    stageA(0);
    advA(192);                       // now points at (r0, phi1)
    stageB(0);
    asm volatile("s_waitcnt vmcnt(0)" ::: "memory");
    __builtin_amdgcn_s_barrier();

    int pidx = 0;
    for (int r = 0; r < 16; ++r) {
        const char* Bb = (const char*)ldsB[r & 1];
#pragma unroll
        for (int phi = 0; phi < 3; ++phi) {
            const int abuf = pidx & 1;
            const char* Ab = (const char*)ldsA[abuf];
            const bool lastPhase = (r == 15) && (phi == 2);

            // ---- 24 ds_read frags (consecutive-16B per lane) ----
            bf16x8 af[3][2][2], bfr[3][2][2];
#pragma unroll
            for (int pp = 0; pp < 3; ++pp)
#pragma unroll
                for (int kk = 0; kk < 2; ++kk) {
                    const int kc = kk * 2 + kc8;
#pragma unroll
                    for (int mf = 0; mf < 2; ++mf) {
                        int co = wm * 64 + mf * 32 + l31;
                        af[pp][mf][kk] = *reinterpret_cast<const bf16x8*>(
                            Ab + (((pp * 4 + kc) * 256 + co) << 4));
                    }
#pragma unroll
                    for (int nf = 0; nf < 2; ++nf) {
                        int p = (wn * 2 + nf + phi) * 34 + l31 + pp;
                        bfr[pp][nf][kk] = *reinterpret_cast<const bf16x8*>(
                            Bb + ((kc * 204 + p) << 4));
                    }
                }

            // ---- stage issues for next phase / next round ----
            if (!lastPhase) {
                stageA(abuf ^ 1);
                advA(phi == 1 ? -380 : 192);
            }
            if (phi == 1 && r < 15) {
#pragma unroll
                for (int k = 0; k < 2; ++k) bsrc[k] += 32;   // next 32-cin grp
                stageB((r + 1) & 1);
            }

            __builtin_amdgcn_s_barrier();
            asm volatile("s_waitcnt lgkmcnt(0)" ::: "memory");
            __builtin_amdgcn_sched_barrier(0);

            __builtin_amdgcn_s_setprio(1);
#pragma unroll
            for (int pp = 0; pp < 3; ++pp)
#pragma unroll
                for (int kk = 0; kk < 2; ++kk) {
                    acc[0][0] = __builtin_amdgcn_mfma_f32_32x32x16_bf16(
                        af[pp][0][kk], bfr[pp][0][kk], acc[0][0], 0, 0, 0);
                    acc[0][1] = __builtin_amdgcn_mfma_f32_32x32x16_bf16(
                        af[pp][0][kk], bfr[pp][1][kk], acc[0][1], 0, 0, 0);
                    acc[1][0] = __builtin_amdgcn_mfma_f32_32x32x16_bf16(
                        af[pp][1][kk], bfr[pp][0][kk], acc[1][0], 0, 0, 0);
                    acc[1][1] = __builtin_amdgcn_mfma_f32_32x32x16_bf16(
                        af[pp][1][kk], bfr[pp][1][kk], acc[1][1], 0, 0, 0);
                }
            __builtin_amdgcn_s_setprio(0);
            __builtin_amdgcn_sched_barrier(0);

            if (!lastPhase) {
                asm volatile("s_waitcnt vmcnt(0)" ::: "memory");
                __builtin_amdgcn_s_barrier();
            }
            ++pidx;
        }
    }

    // ---- epilogue: C/D col=lane&31, row=(q&3)+8*(q>>2)+4*(lane>>5) ----
    const float* db = dsc + b * 512;
#pragma unroll
    for (int mf = 0; mf < 2; ++mf) {
#pragma unroll
        for (int nf = 0; nf < 2; ++nf) {
            const int h = h0 + wn * 2 + nf, w = l31;
#pragma unroll
            for (int q = 0; q < 16; ++q) {
                int row = (q & 3) + 8 * (q >> 2) + 4 * kc8;
                int co  = mt * 256 + wm * 64 + mf * 32 + row;
                out[(((size_t)b * 512 + co) * 32 + h) * 32 + w]
                    = acc[mf][nf][q] * db[co];
            }
        }
    }
}

// ---------------------------------------------------------------------------
extern "C" void kernel_launch(void* const* d_in, const int* in_sizes, int n_in,
                              void* d_out, int out_size, void* d_ws, size_t ws_size,
                              hipStream_t stream) {
    const float* x      = (const float*)d_in[0];
    const float* w      = (const float*)d_in[1];
    const float* mod_w  = (const float*)d_in[2];
    const float* mod_b  = (const float*)d_in[3];
    const float* ln_g   = (const float*)d_in[4];
    const float* ln_b   = (const float*)d_in[5];
    const float* weight = (const float*)d_in[6];
    const float* scale  = (const float*)d_in[7];
    float* out = (float*)d_out;

    char* ws = (char*)d_ws;
    float* s_raw = (float*)(ws);                     // 32 KB, reused as dsc
    float* dsc   = (float*)(ws);
    float* s_eff = (float*)(ws + 32768);             // 32 KB; head reused as zeros page
    float* wsq   = (float*)(ws + 65536);             // 1 MB
    u16*   wbfT  = (u16*)(ws + 65536 + 1048576);     // 4.5 MB
    u16*   xs    = (u16*)(ws + 65536 + 1048576 + 4718592);  // 16.78 MB
    if (ws_size < 22609920u) return;

    lin_kernel <<<2048, 256, 0, stream>>>(w, mod_w, mod_b, s_raw);
    wsq_kernel <<<1024, 256, 0, stream>>>(weight, wsq, wbfT);
    norm_kernel<<<16, 512, 0, stream>>>(s_raw, ln_g, ln_b, scale, s_eff);
    xs_kernel  <<<512, 256, 0, stream>>>(x, s_eff, xs);
    dsc_kernel <<<2048, 256, 0, stream>>>(s_eff, wsq, dsc);
    zfill_kernel<<<1, 1024, 0, stream>>>(s_eff);     // zeros page (s_eff dead now)
    conv_kernel<<<256, 512, 0, stream>>>(wbfT, xs, dsc, (const u16*)s_eff, out);
}